// Round 4
// baseline (434.333 us; speedup 1.0000x reference)
//
#include <hip/hip_runtime.h>

// Fused LSTM(H=128) + 3-layer MLP head, bf16 MFMA (16x16x32), fp32 state.
// B=8192 rows, T=30 steps. 512 blocks x 512 threads (8 waves), 16 rows/block.
// OCCUPANCY DESIGN (rounds 0-3): gfx950 unified VGPR file, 512 regs/SIMD.
//  r3: 28 resident weight frags (112 VGPR) -> total ~150 -> 2 waves/SIMD (22%).
//  r4: keep only the 16 Bzh frags (64 VGPR) resident; STREAM the phase-local
//  frags (x-frag, B1f, B2f = 12 frags) from global (L2-resident, 224KB) each
//  step, issued one phase ahead of use so ~600cy L2 latency hides under the
//  preceding MFMA/epilogue phase. Opaque-pointer asm blocks LICM from
//  re-hoisting the streams into residency. Peak regs ~123 -> fits
//  __launch_bounds__(512,4) cap of 128 -> 2 blocks/CU = 4 waves/SIMD (~44%).
//  Failure signature if cap misses: FETCH_SIZE explosion (spill, round-1 mode).
// - Wave w owns output cols [16w,16w+16); z-GEMM N-tiles at g*128+16w
//   => (i,f,g,o) quadruple + c-state in-lane. 16-row M-tile = one 16x16 tile.
// - x-kstep packs x_hi (k0..7) | x_lo (k8..15), Wi replicated in the B-frag.
// - h/o1 B-frags used for both hi and lo A-panels (same weights).
// - 16x16x32 layouts: A/B: row|col=lane&15, k=(lane>>4)*8+j; C/D: col=lane&15,
//   row=(lane>>4)*4+reg (m89-verified).
// - A-panels [16 rows][40 shorts] (32 data + 8 pad): 16B-aligned b128 reads.
// - Precision identical to passing config: hi/lo split x,h; single-bf16 o1;
//   fp32 acc, gates, o2, head, feedback.

#define T_STEPS 30
#define WARM_N  24

typedef __attribute__((ext_vector_type(8)))  short short8;   // 8 bf16 = 4 VGPRs
typedef __attribute__((ext_vector_type(4)))  float float4v;  // MFMA 16x16 C/D

struct FeatPtrs { const float* f[7]; };

__device__ __forceinline__ short f2bf(float f){
  unsigned u = __float_as_uint(f);
  unsigned r = (u + 0x7fffu + ((u >> 16) & 1u)) >> 16;   // round-nearest-even
  return (short)r;
}
__device__ __forceinline__ float bf2f(short h){
  return __uint_as_float(((unsigned)(unsigned short)h) << 16);
}

#if __has_builtin(__builtin_amdgcn_rcpf)
#define RCP(x) __builtin_amdgcn_rcpf(x)
#else
#define RCP(x) (1.0f/(x))
#endif

__device__ __forceinline__ float sigm(float x){ return RCP(1.0f + __expf(-x)); }
__device__ __forceinline__ float tanh_(float x){ return 1.0f - 2.0f*RCP(1.0f + __expf(2.0f*x)); }

// ---------------- weight pack kernel ----------------
// 224 frags of 512 bf16 (1 KB each), frag elem (lane,j):
//   col16 = lane&15, kk = (lane>>4)*8 + j  (K=32 per fragment)
// frags 0..159 : z-weights [w 0..7][g 0..3][ks 0..4]
//   ks=0: x-frag: kk<8 -> Wi[kk][col], kk 8..15 -> Wi[kk-8][col] (lo replica),
//         kk>=16 -> 0;  ks 1..4: Wh[(ks-1)*32+kk][col];  col = g*128+w*16+col16
// frags 160..191: W1 [w][ks 0..3]: W1[ks*32+kk][w*16+col16]
// frags 192..223: W2 same layout.
__global__ void pack_weights(const float* __restrict__ Wi, const float* __restrict__ Wh,
                             const float* __restrict__ W1, const float* __restrict__ W2,
                             short* __restrict__ ws)
{
  int idx = blockIdx.x * 256 + threadIdx.x;
  if (idx >= 224 * 512) return;
  int f    = idx >> 9;
  int r    = idx & 511;
  int lane = r >> 3, j = r & 7;
  int kk   = ((lane >> 4) << 3) + j;     // 0..31
  int c16  = lane & 15;
  float v = 0.0f;
  if (f < 160){
    int w = f / 20, rem = f % 20, g = rem / 5, ks = rem % 5;
    int col = g * 128 + w * 16 + c16;
    if (ks == 0){
      if (kk < 8)        v = Wi[kk * 512 + col];
      else if (kk < 16)  v = Wi[(kk - 8) * 512 + col];
      else               v = 0.0f;
    } else {
      v = Wh[((ks - 1) * 32 + kk) * 512 + col];
    }
  } else {
    int f2 = f - 160;                    // 0..63
    const float* W = (f2 < 32) ? W1 : W2;
    int f3 = f2 & 31;
    int w = f3 >> 2, ks = f3 & 3;
    v = W[(ks * 32 + kk) * 128 + w * 16 + c16];
  }
  ws[idx] = f2bf(v);
}

// ---------------- main kernel ----------------
__global__ __launch_bounds__(512, 4)
void lstm_mfma(FeatPtrs fp, const float* __restrict__ irr,
               const short* __restrict__ wsb,
               const float* __restrict__ bz, const float* __restrict__ b1,
               const float* __restrict__ b2, const float* __restrict__ Wout,
               const float* __restrict__ bout, float* __restrict__ out)
{
  // A-panels: [kstep][16 rows][40 shorts] (k 0..31 data + 8 pad)
  __shared__ __align__(16) short xp [640];          // x: k0..7 hi, k8..15 lo
  __shared__ __align__(16) short hhi[4 * 640];      // h hi, 4 ksteps
  __shared__ __align__(16) short hlo[4 * 640];      // h lo
  __shared__ __align__(16) short o1p[4 * 640];      // o1 single bf16
  __shared__ __align__(16) float o2s[16 * 132];     // o2 fp32, padded rows
  __shared__ float WoutS[128];
  __shared__ float pS[16];

  const int t   = threadIdx.x;
  const int l   = t & 63;
  const int w   = t >> 6;        // wave 0..7, owns cols [16w,16w+16)
  const int c16 = l & 15;
  const int kq  = l >> 4;        // 0..3
  const int r0  = blockIdx.x * 16;

  const short8* f8 = (const short8*)wsb;

  // resident weights: only the 16 Wh fragments (64 VGPRs)
  short8 Bzh[4][4];
#pragma unroll
  for (int g = 0; g < 4; ++g)
#pragma unroll
    for (int ks = 0; ks < 4; ++ks)
      Bzh[g][ks] = f8[((w * 4 + g) * 5 + 1 + ks) * 64 + l];

  float bzv[4];
#pragma unroll
  for (int g = 0; g < 4; ++g) bzv[g] = bz[g * 128 + w * 16 + c16];
  const float b1v   = b1[w * 16 + c16];
  const float b2v   = b2[w * 16 + c16];
  const float bout0 = bout[0];
  if (t < 128) WoutS[t] = Wout[t];

  { // zero x panel (k16..31 must stay 0) and h panels (h0 = 0)
    int* p = (int*)xp;
    for (int i = t; i < 320;  i += 512) p[i] = 0;
    p = (int*)hhi;
    for (int i = t; i < 1280; i += 512) p[i] = 0;
    p = (int*)hlo;
    for (int i = t; i < 1280; i += 512) p[i] = 0;
  }

  float cst[4];
#pragma unroll
  for (int i = 0; i < 4; ++i) cst[i] = 0.0f;

  const int aoff = c16 * 40 + kq * 8;               // A-frag read offset (shorts)
  const int wb   = (w >> 1) * 640 + (w & 1) * 16 + c16;  // h/o1 write base
  __syncthreads();

  for (int step = 0; step < T_STEPS; ++step){
    // ---- stream x-frags for this step (opaque ptr defeats LICM; loads
    //      issue here, land during gather+barrier+h-MFMAs, used at z end) ----
    const short8* fx = f8;
    asm volatile("" : "+v"(fx));
    short8 Bzx[4];
#pragma unroll
    for (int g = 0; g < 4; ++g) Bzx[g] = fx[((w * 4 + g) * 5) * 64 + l];

    if (t < 128){ // ---- gather 8 input features for 16 rows, split hi/lo ----
      int r = t >> 3, j = t & 7;
      float v;
      if (j < 7)               v = fp.f[j][(r0 + r) * T_STEPS + step];
      else if (step < WARM_N)  v = irr[(r0 + r) * WARM_N + step];
      else                     v = pS[r];               // autoregressive feedback
      int base = r * 40 + j;
      short hi = f2bf(v);
      xp[base]     = hi;
      xp[base + 8] = f2bf(v - bf2f(hi));
    }
    __syncthreads();

    // ---- z = b + [h_hi+h_lo]@Wh + x@Wi  (4 gate tiles in-lane) ----
    float4v acc[4];
#pragma unroll
    for (int g = 0; g < 4; ++g)
#pragma unroll
      for (int r = 0; r < 4; ++r) acc[g][r] = bzv[g];
#pragma unroll
    for (int ks = 0; ks < 4; ++ks){
      short8 ah = *(const short8*)&hhi[ks * 640 + aoff];
      short8 al = *(const short8*)&hlo[ks * 640 + aoff];
#pragma unroll
      for (int g = 0; g < 4; ++g){
        acc[g] = __builtin_amdgcn_mfma_f32_16x16x32_bf16(ah, Bzh[g][ks], acc[g], 0, 0, 0);
        acc[g] = __builtin_amdgcn_mfma_f32_16x16x32_bf16(al, Bzh[g][ks], acc[g], 0, 0, 0);
      }
    }
    {
      short8 ax = *(const short8*)&xp[aoff];
#pragma unroll
      for (int g = 0; g < 4; ++g)
        acc[g] = __builtin_amdgcn_mfma_f32_16x16x32_bf16(ax, Bzx[g], acc[g], 0, 0, 0);
    }
    __syncthreads();   // all panel reads done before h rewrite

    // ---- stream B1 frags (land during gates epilogue + barrier) ----
    const short8* f1 = f8;
    asm volatile("" : "+v"(f1));
    short8 B1f[4];
#pragma unroll
    for (int ks = 0; ks < 4; ++ks) B1f[ks] = f1[(160 + w * 4 + ks) * 64 + l];

    // ---- gates (fp32, in-lane), update c, write h hi/lo panels ----
#pragma unroll
    for (int r = 0; r < 4; ++r){
      float zi = acc[0][r], zf = acc[1][r], zg = acc[2][r], zo = acc[3][r];
      float c2 = sigm(zf) * cst[r] + sigm(zi) * tanh_(zg);
      cst[r] = c2;
      float h2 = sigm(zo) * tanh_(c2);
      int addr = wb + (kq * 4 + r) * 40;              // row = kq*4+r (C/D map)
      short hi = f2bf(h2);
      hhi[addr] = hi;
      hlo[addr] = f2bf(h2 - bf2f(hi));
    }
    __syncthreads();

    // ---- MLP1: o1 = relu(h@W1 + b1) ----
    float4v m1;
#pragma unroll
    for (int r = 0; r < 4; ++r) m1[r] = b1v;
#pragma unroll
    for (int ks = 0; ks < 4; ++ks){
      short8 ah = *(const short8*)&hhi[ks * 640 + aoff];
      m1 = __builtin_amdgcn_mfma_f32_16x16x32_bf16(ah, B1f[ks], m1, 0, 0, 0);
      short8 al = *(const short8*)&hlo[ks * 640 + aoff];
      m1 = __builtin_amdgcn_mfma_f32_16x16x32_bf16(al, B1f[ks], m1, 0, 0, 0);
    }

    // ---- stream B2 frags (land during o1 write + barrier) ----
    const short8* f2p = f8;
    asm volatile("" : "+v"(f2p));
    short8 B2f[4];
#pragma unroll
    for (int ks = 0; ks < 4; ++ks) B2f[ks] = f2p[(192 + w * 4 + ks) * 64 + l];

#pragma unroll
    for (int r = 0; r < 4; ++r){
      int addr = wb + (kq * 4 + r) * 40;
      o1p[addr] = f2bf(fmaxf(m1[r], 0.0f));
    }
    __syncthreads();

    // ---- MLP2: o2 = relu(o1@W2 + b2), store fp32 ----
    float4v m2;
#pragma unroll
    for (int r = 0; r < 4; ++r) m2[r] = b2v;
#pragma unroll
    for (int ks = 0; ks < 4; ++ks){
      short8 a = *(const short8*)&o1p[ks * 640 + aoff];
      m2 = __builtin_amdgcn_mfma_f32_16x16x32_bf16(a, B2f[ks], m2, 0, 0, 0);
    }
#pragma unroll
    for (int r = 0; r < 4; ++r)
      o2s[(kq * 4 + r) * 132 + w * 16 + c16] = fmaxf(m2[r], 0.0f);
    __syncthreads();

    // ---- head: p = o2 . Wout + bout (fp32 exact), 8 threads/row ----
    if (t < 128){
      int r = t >> 3, jj = t & 7;
      const float* orow = &o2s[r * 132 + jj * 16];
      const float* wrow = &WoutS[jj * 16];
      float s = 0.0f;
#pragma unroll
      for (int q = 0; q < 16; ++q) s += orow[q] * wrow[q];
      s += __shfl_down(s, 4, 8);
      s += __shfl_down(s, 2, 8);
      s += __shfl_down(s, 1, 8);
      if (jj == 0){
        float p = s + bout0;
        out[(r0 + r) * T_STEPS + step] = p;
        pS[r] = p;
      }
    }
    __syncthreads();   // pS/panels visible before next step
  }
}

extern "C" void kernel_launch(void* const* d_in, const int* in_sizes, int n_in,
                              void* d_out, int out_size, void* d_ws, size_t ws_size,
                              hipStream_t stream)
{
  (void)in_sizes; (void)n_in; (void)out_size; (void)ws_size;
  // inputs: 0..7 weather (unused), 8..14 time feats, 15 irradiance_in,
  // 16 Wi, 17 Wh, 18 b, 19 W1, 20 b1, 21 W2, 22 b2, 23 Wout, 24 bout
  FeatPtrs fp;
  for (int j = 0; j < 7; ++j) fp.f[j] = (const float*)d_in[8 + j];
  const float* irr  = (const float*)d_in[15];
  const float* Wi   = (const float*)d_in[16];
  const float* Wh   = (const float*)d_in[17];
  const float* bz   = (const float*)d_in[18];
  const float* W1   = (const float*)d_in[19];
  const float* b1   = (const float*)d_in[20];
  const float* W2   = (const float*)d_in[21];
  const float* b2   = (const float*)d_in[22];
  const float* Wout = (const float*)d_in[23];
  const float* bout = (const float*)d_in[24];

  short* ws = (short*)d_ws;                       // 224*512*2 = 224 KB used
  pack_weights<<<dim3(448), dim3(256), 0, stream>>>(Wi, Wh, W1, W2, ws);
  lstm_mfma<<<dim3(512), dim3(512), 0, stream>>>(
      fp, irr, ws, bz, b1, b2, Wout, bout, (float*)d_out);
}